// Round 10
// baseline (259.616 us; speedup 1.0000x reference)
//
#include <hip/hip_runtime.h>
#include <math.h>

#define B_ 4
#define T_ 2048
#define D_ 512
#define H_ 8
#define DH_ 64
#define BT_ 8192
#define FF_ 2048
#define EPS_ 1e-5f
#define SCALE_ 0.04419417382415922f   // 512^-0.5
#define SC2_ 0.06375861151f           // SCALE_ * log2(e)
#define NEGINF_ -1e30f

typedef short b16x8 __attribute__((ext_vector_type(8)));
typedef short b16x4 __attribute__((ext_vector_type(4)));
typedef float f32x4 __attribute__((ext_vector_type(4)));

#define MFMA16(a, b, c) __builtin_amdgcn_mfma_f32_16x16x32_bf16(a, b, c, 0, 0, 0)
#define MFMA16K16(a, b, c) __builtin_amdgcn_mfma_f32_16x16x16bf16_1k(a, b, c, 0, 0, 0)

#define GLL16(gp, lp) \
    __builtin_amdgcn_global_load_lds((const __attribute__((address_space(1))) void*)(gp), \
                                     (__attribute__((address_space(3))) void*)(lp), 16, 0, 0)

#if __has_builtin(__builtin_amdgcn_exp2f)
#define EXP2F(x) __builtin_amdgcn_exp2f(x)
#else
#define EXP2F(x) exp2f(x)
#endif

// fp32 -> bf16 RNE (finite inputs)
static __device__ inline short f2bf(float f) {
    unsigned int u = __builtin_bit_cast(unsigned int, f);
    unsigned int r = (u + 0x7fffu + ((u >> 16) & 1u)) >> 16;
    return (short)r;
}
// fp32 -> bf16 truncation (1 VALU op; used for P where bias is negligible)
static __device__ inline short f2bf_trunc(float f) {
    return (short)(__builtin_bit_cast(unsigned int, f) >> 16);
}
// bf16 -> fp32
static __device__ inline float bf2f(short s) {
    return __builtin_bit_cast(float, ((unsigned int)(unsigned short)s) << 16);
}

// ---------------------------------------------------------------------------
// Prologue: weight transposes (blocks 0..3071) + LN1 of x (blocks 3072..5119).
// block (32,8) = 256 threads.
// ---------------------------------------------------------------------------
__global__ __launch_bounds__(256) void prologue_kernel(
        const float* __restrict__ Wq, const float* __restrict__ Wk,
        const float* __restrict__ Wv, const float* __restrict__ Wp,
        const float* __restrict__ W1, const float* __restrict__ W2,
        short* __restrict__ wqkv, short* __restrict__ wpt,
        short* __restrict__ w1t, short* __restrict__ w2t,
        const float* __restrict__ X, const float* __restrict__ G,
        const float* __restrict__ Bb, short* __restrict__ Y)
{
    __shared__ float tile[32][33];
    int idx = blockIdx.x;
    if (idx >= 3072) {
        // LayerNorm: 4 rows/block, one row per wave
        int tid = threadIdx.y * 32 + threadIdx.x;
        int wave = tid >> 6, t = tid & 63;
        int row = (idx - 3072) * 4 + wave;
        const float* xr = X + (size_t)row * D_;
        float4 v0 = *(const float4*)(xr + t * 4);
        float4 v1 = *(const float4*)(xr + 256 + t * 4);
        float sum = v0.x + v0.y + v0.z + v0.w + v1.x + v1.y + v1.z + v1.w;
        float ssq = v0.x*v0.x + v0.y*v0.y + v0.z*v0.z + v0.w*v0.w
                  + v1.x*v1.x + v1.y*v1.y + v1.z*v1.z + v1.w*v1.w;
        #pragma unroll
        for (int off = 32; off > 0; off >>= 1) {
            sum += __shfl_down(sum, off);
            ssq += __shfl_down(ssq, off);
        }
        sum = __shfl(sum, 0);
        ssq = __shfl(ssq, 0);
        float mean = sum * (1.0f / D_);
        float var  = ssq * (1.0f / D_) - mean * mean;
        float rstd = rsqrtf(var + EPS_);
        float4 g0 = *(const float4*)(G + t * 4);
        float4 g1 = *(const float4*)(G + 256 + t * 4);
        float4 b0 = *(const float4*)(Bb + t * 4);
        float4 b1 = *(const float4*)(Bb + 256 + t * 4);
        short4 o0, o1;
        o0.x = f2bf((v0.x - mean) * rstd * g0.x + b0.x);
        o0.y = f2bf((v0.y - mean) * rstd * g0.y + b0.y);
        o0.z = f2bf((v0.z - mean) * rstd * g0.z + b0.z);
        o0.w = f2bf((v0.w - mean) * rstd * g0.w + b0.w);
        o1.x = f2bf((v1.x - mean) * rstd * g1.x + b1.x);
        o1.y = f2bf((v1.y - mean) * rstd * g1.y + b1.y);
        o1.z = f2bf((v1.z - mean) * rstd * g1.z + b1.z);
        o1.w = f2bf((v1.w - mean) * rstd * g1.w + b1.w);
        short* yr = Y + (size_t)row * D_;
        *(short4*)(yr + t * 4)       = o0;
        *(short4*)(yr + 256 + t * 4) = o1;
        return;
    }
    const float* src; short* dst; int R, C, tx0, ty0;
    if (idx < 768) {            // Wq/Wk/Wv: per head [512][64] -> [64][512]
        int w = idx >> 8, rem = idx & 255;
        int hh = rem >> 5, t = rem & 31;
        const float* base = (w == 0) ? Wq : ((w == 1) ? Wk : Wv);
        src = base + hh * (D_ * DH_);
        dst = wqkv + w * (512 * 512) + hh * (DH_ * D_);
        R = 512; C = 64; tx0 = (t & 1) * 32; ty0 = (t >> 1) * 32;
    } else if (idx < 1024) {    // Wproj [512][512]
        int t = idx - 768;
        src = Wp; dst = wpt; R = 512; C = 512;
        tx0 = (t & 15) * 32; ty0 = (t >> 4) * 32;
    } else if (idx < 2048) {    // W1 [512][2048] -> [2048][512]
        int t = idx - 1024;
        src = W1; dst = w1t; R = 512; C = 2048;
        tx0 = (t & 63) * 32; ty0 = (t >> 6) * 32;
    } else {                    // W2 [2048][512] -> [512][2048]
        int t = idx - 2048;
        src = W2; dst = w2t; R = 2048; C = 512;
        tx0 = (t & 15) * 32; ty0 = (t >> 4) * 32;
    }
    int tx = threadIdx.x, ty = threadIdx.y;
    #pragma unroll
    for (int i = 0; i < 32; i += 8)
        tile[ty + i][tx] = src[(size_t)(ty0 + ty + i) * C + tx0 + tx];
    __syncthreads();
    #pragma unroll
    for (int i = 0; i < 32; i += 8)
        dst[(size_t)(tx0 + ty + i) * R + ty0 + tx] = f2bf(tile[tx][ty + i]);
}

// ---------------------------------------------------------------------------
// LayerNorm over bf16 input (x1 path): 4 rows/block, one row per wave.
// ---------------------------------------------------------------------------
__global__ __launch_bounds__(256) void ln_bf16_kernel(const short* __restrict__ X,
        const float* __restrict__ G, const float* __restrict__ Bb,
        short* __restrict__ Y)
{
    int wave = threadIdx.x >> 6, t = threadIdx.x & 63;
    int row = blockIdx.x * 4 + wave;
    const short* xr = X + (size_t)row * D_ + t * 8;
    b16x8 xv = *(const b16x8*)xr;
    float v[8];
    float sum = 0.0f, ssq = 0.0f;
    #pragma unroll
    for (int e = 0; e < 8; ++e) {
        v[e] = bf2f(xv[e]);
        sum += v[e];
        ssq += v[e] * v[e];
    }
    #pragma unroll
    for (int off = 32; off > 0; off >>= 1) {
        sum += __shfl_down(sum, off);
        ssq += __shfl_down(ssq, off);
    }
    sum = __shfl(sum, 0);
    ssq = __shfl(ssq, 0);
    float mean = sum * (1.0f / D_);
    float var  = ssq * (1.0f / D_) - mean * mean;
    float rstd = rsqrtf(var + EPS_);

    float4 g0 = *(const float4*)(G + t * 8);
    float4 g1 = *(const float4*)(G + t * 8 + 4);
    float4 b0 = *(const float4*)(Bb + t * 8);
    float4 b1 = *(const float4*)(Bb + t * 8 + 4);
    float gg[8] = {g0.x, g0.y, g0.z, g0.w, g1.x, g1.y, g1.z, g1.w};
    float bb[8] = {b0.x, b0.y, b0.z, b0.w, b1.x, b1.y, b1.z, b1.w};
    b16x8 o;
    #pragma unroll
    for (int e = 0; e < 8; ++e)
        o[e] = f2bf((v[e] - mean) * rstd * gg[e] + bb[e]);
    *(b16x8*)(Y + (size_t)row * D_ + t * 8) = o;
}

// ---------------------------------------------------------------------------
// bf16 MFMA GEMM, 256x256, BK=64, 512 threads / 8 waves (2M x 4N).
// 2-phase 256^2 geometry from verified parts (R7). 128 KB LDS -> 1 block/CU.
// ---------------------------------------------------------------------------
__global__ __launch_bounds__(512, 2) void mm256_kernel(const short* __restrict__ A,
        const short* __restrict__ Bt, void* __restrict__ C,
        const float* __restrict__ bias, int relu, int N, int K)
{
    __shared__ short As[2][256 * 64];   // 64 KB
    __shared__ short Bs[2][256 * 64];   // 64 KB
    const int tid = threadIdx.x;
    const int wave = tid >> 6, lane = tid & 63;
    const int quad = lane >> 4, l15 = lane & 15;
    const int m0 = blockIdx.x * 256, n0 = blockIdx.y * 256;
    const int mw = (wave & 1) * 128, nw = (wave >> 1) * 64;

#define STAGE_M256(bufi, kk) \
    { \
        for (int r = 0; r < 4; ++r) { \
            int c = r * 512 + tid; \
            int row = c >> 3, seg = (c & 7) ^ (row & 7); \
            GLL16(A + (size_t)(m0 + row) * K + (kk) + seg * 8, \
                  As[bufi] + (size_t)(r * 512 + wave * 64) * 8); \
            GLL16(Bt + (size_t)(n0 + row) * K + (kk) + seg * 8, \
                  Bs[bufi] + (size_t)(r * 512 + wave * 64) * 8); \
        } \
    }

    f32x4 acc[8][4];
    #pragma unroll
    for (int i = 0; i < 8; ++i)
        #pragma unroll
        for (int j = 0; j < 4; ++j)
            acc[i][j] = (f32x4){0.f, 0.f, 0.f, 0.f};

    const int NT = K >> 6;   // 8 for K=512
    STAGE_M256(0, 0);
    int buf = 0;
    for (int t = 0; t < NT; ++t) {
        __syncthreads();     // stage(buf) landed (vmcnt0 drain); prev reads done
        if (t + 1 < NT) STAGE_M256(buf ^ 1, (t + 1) * 64);
        #pragma unroll
        for (int kb = 0; kb < 2; ++kb) {
            b16x8 af[8], bf[4];
            #pragma unroll
            for (int i = 0; i < 8; ++i) {
                int row = mw + i * 16 + l15;
                af[i] = *(const b16x8*)(As[buf] + row * 64 + (((kb * 4 + quad) ^ (row & 7)) * 8));
            }
            #pragma unroll
            for (int j = 0; j < 4; ++j) {
                int row = nw + j * 16 + l15;
                bf[j] = *(const b16x8*)(Bs[buf] + row * 64 + (((kb * 4 + quad) ^ (row & 7)) * 8));
            }
            #pragma unroll
            for (int i = 0; i < 8; ++i)
                #pragma unroll
                for (int j = 0; j < 4; ++j)
                    acc[i][j] = MFMA16(af[i], bf[j], acc[i][j]);
        }
        buf ^= 1;
    }
#undef STAGE_M256

    #pragma unroll
    for (int i = 0; i < 8; ++i) {
        #pragma unroll
        for (int r = 0; r < 4; ++r) {
            size_t row = (size_t)(m0 + mw + i * 16 + quad * 4 + r);
            #pragma unroll
            for (int j = 0; j < 4; ++j) {
                int col = n0 + nw + j * 16 + l15;
                float v = acc[i][j][r];
                if (bias)  v += bias[col];
                if (relu)  v = fmaxf(v, 0.0f);
                ((short*)C)[row * N + col] = f2bf(v);
            }
        }
    }
}

// ---------------------------------------------------------------------------
// bf16 MFMA GEMM, 64x64, BK=64 dbuf pipeline (proj, FFN2). grid=(M/64, N/64).
// 32 KB LDS keeps 4 blk/CU. Chunk swizzle f(row)=row&7 (conflict-free).
// ---------------------------------------------------------------------------
__global__ __launch_bounds__(256) void mm6464_kernel(const short* __restrict__ A,
        const short* __restrict__ Bt, void* __restrict__ C,
        const float* __restrict__ bias, const void* __restrict__ resid,
        int M, int N, int K, int relu, int out_bf16, int resid_bf16)
{
    __shared__ short As[2][64 * 64];
    __shared__ short Bs[2][64 * 64];
    const int tid = threadIdx.x;
    const int wave = tid >> 6, lane = tid & 63;
    const int quad = lane >> 4, l15 = lane & 15;
    const int m0 = blockIdx.x * 64, n0 = blockIdx.y * 64;
    const int nw = wave * 16;

#define STAGE_M66(bufi, kk) \
    { \
        for (int r = 0; r < 2; ++r) { \
            int c = r * 256 + tid; \
            int row = c >> 3, seg = (c & 7) ^ (row & 7); \
            GLL16(A + (size_t)(m0 + row) * K + (kk) + seg * 8, \
                  As[bufi] + (size_t)(r * 256 + wave * 64) * 8); \
            GLL16(Bt + (size_t)(n0 + row) * K + (kk) + seg * 8, \
                  Bs[bufi] + (size_t)(r * 256 + wave * 64) * 8); \
        } \
    }

    f32x4 acc[4];
    #pragma unroll
    for (int i = 0; i < 4; ++i) acc[i] = (f32x4){0.f, 0.f, 0.f, 0.f};

    STAGE_M66(0, 0);
    int buf = 0;
    for (int k0 = 0; k0 < K; k0 += 64) {
        __syncthreads();
        if (k0 + 64 < K) STAGE_M66(buf ^ 1, k0 + 64);
        b16x8 af[4][2], bf[2];
        #pragma unroll
        for (int i = 0; i < 4; ++i)
            #pragma unroll
            for (int kb = 0; kb < 2; ++kb) {
                int row = i * 16 + l15;
                af[i][kb] = *(const b16x8*)(As[buf] + row * 64 + (((kb * 4 + quad) ^ (row & 7)) * 8));
            }
        #pragma unroll
        for (int kb = 0; kb < 2; ++kb) {
            int row = nw + l15;
            bf[kb] = *(const b16x8*)(Bs[buf] + row * 64 + (((kb * 4 + quad) ^ (row & 7)) * 8));
        }
        #pragma unroll
        for (int kb = 0; kb < 2; ++kb)
            #pragma unroll
            for (int i = 0; i < 4; ++i)
                acc[i] = MFMA16(af[i][kb], bf[kb], acc[i]);
        buf ^= 1;
    }
#undef STAGE_M66

    #pragma unroll
    for (int i = 0; i < 4; ++i) {
        #pragma unroll
        for (int r = 0; r < 4; ++r) {
            size_t row = (size_t)(m0 + i * 16 + quad * 4 + r);
            int col = n0 + nw + l15;
            float v = acc[i][r];
            if (bias)  v += bias[col];
            if (resid) {
                if (resid_bf16) v += bf2f(((const short*)resid)[row * N + col]);
                else            v += ((const float*)resid)[row * N + col];
            }
            if (relu)  v = fmaxf(v, 0.0f);
            if (out_bf16) ((short*)C)[row * N + col] = f2bf(v);
            else          ((float*)C)[row * N + col] = v;
        }
    }
}

// ---------------------------------------------------------------------------
// Flash attention, S^T formulation, SPLIT-K x2, STATIC-MAX softmax (m == 0).
// R9 = R8 (QBLK=128) + the NaN fix: at qb=0, split 1 (tokens 64..127) is
// FULLY masked for q-rows 0..63 -> lrow==0 -> 1/lrow=inf -> 0*inf=NaN in
// the partial. Guard: inv = lrow>0 ? 1/lrow : 0, giving a zero partial with
// zero weight (row-granular analog of R0's empty-split special case).
// All other structure identical to R8 (see its header comment).
// ---------------------------------------------------------------------------
__global__ __launch_bounds__(256) void attn_kernel(const short* __restrict__ qkv,
        short* __restrict__ Opart, float* __restrict__ Ml)
{
    __shared__ short smem[16384];   // Qs [0,8192) | Ks [8192,12288) | Vt [12288,16384)
    short* Qs = smem;
    short* Ks = smem + 8192;
    short* Vt = smem + 12288;

    const int tid = threadIdx.x;
    const int wave = tid >> 6, lane = tid & 63;
    const int quad = lane >> 4, l15 = lane & 15;
    const int bh = blockIdx.x;
    const int qb = 15 - (int)blockIdx.y;      // long blocks first
    const int split = blockIdx.z;
    const int b = bh >> 3, h = bh & 7;
    const size_t tok0 = (size_t)b * T_;
    const int half = qb + 1;
    const int klo = split ? half : 0;
    const int khi = split ? 2 * qb + 2 : half;
    const int pidx = split * 512 + bh * 16 + qb;
    short* Op = Opart + (size_t)pidx * 8192;
    float* mlp = Ml + (size_t)pidx * 128;

    // stage Q tile 128x64 (chunk-swizzled), 4 GLL per thread
    #pragma unroll
    for (int r = 0; r < 4; ++r) {
        int c = r * 256 + tid;
        int tk = c >> 3;
        int seg = (c & 7) ^ (tk & 7);
        GLL16(qkv + (tok0 + qb * 128 + tk) * 1536 + h * 64 + seg * 8,
              Qs + (size_t)(r * 256 + wave * 64) * 8);
    }

    float lrow[2] = {0.0f, 0.0f};
    f32x4 ot[4][2];   // O^T: row=dh=dt*16+quad*4+rr, col=q (qg*16 groups), lane l15
    #pragma unroll
    for (int dt = 0; dt < 4; ++dt)
        #pragma unroll
        for (int qg = 0; qg < 2; ++qg)
            ot[dt][qg] = (f32x4){0.f, 0.f, 0.f, 0.f};

    b16x8 qf[2][2];   // [qg][kb]
    const int qrel0 = wave * 32 + l15;   // + qg*16

    for (int kj = klo; kj < khi; ++kj) {
        __syncthreads();   // prev-iter LDS reads done (and Q GLL drained on first)
        // stage K tile (swizzled)
        #pragma unroll
        for (int r = 0; r < 2; ++r) {
            int c = r * 256 + tid;
            int tk = c >> 3;
            int seg = (c & 7) ^ (tk & 7);
            GLL16(qkv + (tok0 + kj * 64 + tk) * 1536 + 512 + h * 64 + seg * 8,
                  Ks + (size_t)(r * 256 + wave * 64) * 8);
        }
        // stage V transposed, granule-swizzled: thread = (s 0..7, tp 0..31)
        {
            int s = tid >> 5, tp = tid & 31;
            const short* g0 = qkv + (tok0 + kj * 64 + tp * 2) * 1536 + 1024 + h * 64 + s * 8;
            b16x8 v0 = *(const b16x8*)g0;
            b16x8 v1 = *(const b16x8*)(g0 + 1536);
            int* vo = (int*)Vt;
            int gg = tp >> 1, hlf = tp & 1;
            #pragma unroll
            for (int e = 0; e < 8; ++e) {
                int row = s * 8 + e;
                unsigned int pk = (unsigned int)(unsigned short)v0[e]
                                | ((unsigned int)(unsigned short)v1[e] << 16);
                vo[row * 32 + ((gg ^ (row & 15)) << 1) + hlf] = pk;
            }
        }
        __syncthreads();

        if (kj == klo) {   // Q fragments (B-operand: n=l15, k=kb*32+quad*8+j), hoisted
            #pragma unroll
            for (int qg = 0; qg < 2; ++qg)
                #pragma unroll
                for (int kb = 0; kb < 2; ++kb) {
                    int row = qrel0 + qg * 16;
                    qf[qg][kb] = *(const b16x8*)(Qs + row * 64 + (((kb * 4 + quad) ^ (row & 7)) * 8));
                }
        }

        // S^T = K Q^T  (A=K-frag shared across qg, B=Q-frag)
        f32x4 st[4][2];   // [mt][qg]: token = mt*16+quad*4+r, q = qg-group col l15
        #pragma unroll
        for (int mt = 0; mt < 4; ++mt)
            #pragma unroll
            for (int qg = 0; qg < 2; ++qg)
                st[mt][qg] = (f32x4){0.f, 0.f, 0.f, 0.f};
        #pragma unroll
        for (int mt = 0; mt < 4; ++mt) {
            int trow = mt * 16 + l15;
            #pragma unroll
            for (int kb = 0; kb < 2; ++kb) {
                b16x8 kf = *(const b16x8*)(Ks + trow * 64 + (((kb * 4 + quad) ^ (trow & 7)) * 8));
                #pragma unroll
                for (int qg = 0; qg < 2; ++qg)
                    st[mt][qg] = MFMA16(kf, qf[qg][kb], st[mt][qg]);
            }
        }

        // causal mask + P = exp2(S*SC2) (no max subtraction)
        const bool need_mask = (kj >= 2 * qb);
        const int moff = kj * 64 - qb * 128;   // token_abs - qblock_base
        float rs[2] = {0.0f, 0.0f};
        b16x4 pf[4][2];   // [mt][qg]: P^T fragments in 16x16x16 B-operand layout
        #pragma unroll
        for (int mt = 0; mt < 4; ++mt)
            #pragma unroll
            for (int qg = 0; qg < 2; ++qg)
                #pragma unroll
                for (int r = 0; r < 4; ++r) {
                    float s = st[mt][qg][r];
                    if (need_mask && (moff + mt * 16 + quad * 4 + r) > (qrel0 + qg * 16)) s = NEGINF_;
                    float e = EXP2F(s * SC2_);
                    rs[qg] += e;
                    pf[mt][qg][r] = f2bf_trunc(e);
                }
        #pragma unroll
        for (int qg = 0; qg < 2; ++qg) {
            rs[qg] += __shfl_xor(rs[qg], 16);
            rs[qg] += __shfl_xor(rs[qg], 32);
            lrow[qg] += rs[qg];
        }

        // O^T += V^T P^T  (V-frags register-shared across qg)
        #pragma unroll
        for (int dt = 0; dt < 4; ++dt) {
            const short* vrow = Vt + (dt * 16 + l15) * 64;
            b16x4 vf[4];
            #pragma unroll
            for (int kt = 0; kt < 4; ++kt)
                vf[kt] = *(const b16x4*)(vrow + (((kt * 4 + quad) ^ l15) << 2));
            #pragma unroll
            for (int qg = 0; qg < 2; ++qg)
                #pragma unroll
                for (int kt = 0; kt < 4; ++kt)
                    ot[dt][qg] = MFMA16K16(vf[kt], pf[kt][qg], ot[dt][qg]);
        }
    }

    // epilogue: normalize, repack via per-wave LDS strip (aliases all smem)
    __syncthreads();   // all waves done reading Qs/Ks/Vt
    short* strip = smem;   // 128 rows x 72 shorts = 18 KB <= 32 KB
    #pragma unroll
    for (int qg = 0; qg < 2; ++qg) {
        // NaN fix: fully-masked rows (qb=0, split=1, rows 0..63) have lrow==0;
        // emit a zero partial (combine weight l2 is also 0) instead of inf*0.
        float inv = (lrow[qg] > 0.0f) ? 1.0f / lrow[qg] : 0.0f;
        int qr = qrel0 + qg * 16;
        #pragma unroll
        for (int dt = 0; dt < 4; ++dt) {
            b16x4 o4;
            o4[0] = f2bf(ot[dt][qg][0] * inv);
            o4[1] = f2bf(ot[dt][qg][1] * inv);
            o4[2] = f2bf(ot[dt][qg][2] * inv);
            o4[3] = f2bf(ot[dt][qg][3] * inv);
            *(b16x4*)(strip + (size_t)qr * 72 + dt * 16 + quad * 4) = o4;
        }
    }
    // rows tid>>1 (= wave*32..wave*32+31) are this wave's own rows -> DS
    // in-order within the wave, no extra barrier
    {
        int row = tid >> 1, ch = tid & 1;   // 2 chunks of 32 shorts per row
        const short* sp = strip + (size_t)row * 72 + ch * 32;
        short* dst = Op + row * 64 + ch * 32;
        *(b16x8*)(dst)      = *(const b16x8*)(sp);
        *(b16x8*)(dst + 8)  = *(const b16x8*)(sp + 8);
        *(b16x8*)(dst + 16) = *(const b16x8*)(sp + 16);
        *(b16x8*)(dst + 24) = *(const b16x8*)(sp + 24);
    }
    if (quad == 0) {
        mlp[qrel0]      = lrow[0];
        mlp[qrel0 + 16] = lrow[1];
    }
}

// ---------------------------------------------------------------------------
// Combine the two attn split-K partials: O = (l1*O1 + l2*O2)/(l1+l2).
// grid 512 (one (bh,qb) per block, 128x64 tile), 256 threads.
// l1 > 0 always (split 0 contains the diagonal for every row), so the
// denominator is safe; l2 may be 0 (qb=0 rows 0..63) with O2 = 0.
// ---------------------------------------------------------------------------
__global__ __launch_bounds__(256) void attn_combine_kernel(
        const short* __restrict__ Opart, const float* __restrict__ Ml,
        short* __restrict__ Ob)
{
    int pair = blockIdx.x;              // bh*16 + qb
    int bh = pair >> 4, qb = pair & 15;
    int b = bh >> 3, h = bh & 7;
    int tid = threadIdx.x;
    const short* O1 = Opart + (size_t)pair * 8192;
    const short* O2 = Opart + (size_t)(512 + pair) * 8192;
    const float* ml1 = Ml + (size_t)pair * 128;
    const float* ml2 = Ml + (size_t)(512 + pair) * 128;
    int ch = tid & 7;                   // 8 shorts per chunk
    #pragma unroll
    for (int it = 0; it < 4; ++it) {
        int row = it * 32 + (tid >> 3);
        float l1 = ml1[row], l2 = ml2[row];
        float inv = 1.0f / (l1 + l2);
        float w1 = l1 * inv, w2 = l2 * inv;
        b16x8 a = *(const b16x8*)(O1 + row * 64 + ch * 8);
        b16x8 c = *(const b16x8*)(O2 + row * 64 + ch * 8);
        b16x8 o;
        #pragma unroll
        for (int e = 0; e < 8; ++e)
            o[e] = f2bf(w1 * bf2f(a[e]) + w2 * bf2f(c[e]));
        short* dst = Ob + ((size_t)(b * T_ + qb * 128 + row)) * 512 + h * 64 + ch * 8;
        *(b16x8*)dst = o;
    }
}

// ---------------------------------------------------------------------------
extern "C" void kernel_launch(void* const* d_in, const int* in_sizes, int n_in,
                              void* d_out, int out_size, void* d_ws, size_t ws_size,
                              hipStream_t stream) {
    (void)in_sizes; (void)n_in; (void)out_size; (void)ws_size;
    const float* x     = (const float*)d_in[0];
    const float* ln_g  = (const float*)d_in[1];
    const float* ln_b  = (const float*)d_in[2];
    const float* Wq    = (const float*)d_in[3];
    const float* Wk    = (const float*)d_in[4];
    const float* Wv    = (const float*)d_in[5];
    const float* Wproj = (const float*)d_in[6];
    const float* bproj = (const float*)d_in[7];
    const float* W1    = (const float*)d_in[8];
    const float* b1    = (const float*)d_in[9];
    const float* W2    = (const float*)d_in[10];
    const float* b2    = (const float*)d_in[11];
    float* out = (float*)d_out;

    char* W = (char*)d_ws;
    short* hbuf  = (short*)(W + 0);                    // 8 MB  (LN out, bf16)
    short* qkvb  = (short*)(W + ((size_t)8  << 20));   // 24 MB [BT][1536]
    short* attno = (short*)(W + ((size_t)32 << 20));   // 8 MB  [BT][512]
    short* x1b   = (short*)(W + ((size_t)40 << 20));   // 8 MB  [BT][512] bf16
    short* ff1   = (short*)(W + ((size_t)56 << 20));   // 32 MB [BT][2048]
    short* wqkv  = (short*)(W + ((size_t)88 << 20));   // 1.5 MB [1536][512]
    short* wpt   = (short*)(W + ((size_t)90 << 20));   // 0.5 MB [512][512]
    short* w1t   = (short*)(W + ((size_t)91 << 20));   // 2 MB  [2048][512]
    short* w2t   = (short*)(W + ((size_t)93 << 20));   // 2 MB  [512][2048]
    short* Opart = (short*)(W + ((size_t)96 << 20));   // 16 MB [2][512][128][64] bf16
    float* Ml    = (float*)(W + ((size_t)112 << 20));  // 0.5 MB [2][512][128] fp32

    // 0. weight transposes + LN1 fused in one launch
    prologue_kernel<<<dim3(3072 + BT_ / 4), dim3(32, 8), 0, stream>>>(
        Wq, Wk, Wv, Wproj, W1, W2, wqkv, wpt, w1t, w2t,
        x, ln_g, ln_b, hbuf);
    // 1. qkv = h @ Wqkv  [8192,1536] bf16  (256x256 tiles -> 192 blocks)
    mm256_kernel<<<dim3(32, 6), dim3(512), 0, stream>>>(hbuf, wqkv, qkvb,
        nullptr, 0, 1536, D_);
    // 2. attention QBLK=128 split-K x2 -> partials, then combine -> attno bf16
    attn_kernel<<<dim3(32, 16, 2), dim3(256), 0, stream>>>(qkvb, Opart, Ml);
    attn_combine_kernel<<<dim3(512), dim3(256), 0, stream>>>(Opart, Ml, attno);
    // 3. x1b = bf16(x + attno @ Wproj + bproj)   (BK=64 -> 16 iters)
    mm6464_kernel<<<dim3(128, 8), dim3(256), 0, stream>>>(attno, wpt, x1b,
        bproj, x, BT_, D_, D_, 0, 1, 0);
    // 4. h2 = LN(x1b) -> bf16 (reuse hbuf)
    ln_bf16_kernel<<<dim3(BT_ / 4), dim3(256), 0, stream>>>(x1b, ln_g, ln_b, hbuf);
    // 5. ff1 = relu(h2 @ W1 + b1)  bf16  (256x256 tiles -> 256 blocks = 1/CU)
    mm256_kernel<<<dim3(32, 8), dim3(512), 0, stream>>>(hbuf, w1t, ff1,
        b1, 1, FF_, D_);
    // 6. out = x1b + ff1 @ W2 + b2  (fp32 out, bf16 resid, BK=64 -> 32 iters)
    mm6464_kernel<<<dim3(128, 8), dim3(256), 0, stream>>>(ff1, w2t, out,
        b2, x1b, BT_, D_, FF_, 0, 0, 1);
}

// Round 11
// 256.355 us; speedup vs baseline: 1.0127x; 1.0127x over previous
//
#include <hip/hip_runtime.h>
#include <math.h>

#define B_ 4
#define T_ 2048
#define D_ 512
#define H_ 8
#define DH_ 64
#define BT_ 8192
#define FF_ 2048
#define EPS_ 1e-5f
#define SCALE_ 0.04419417382415922f   // 512^-0.5
#define SC2_ 0.06375861151f           // SCALE_ * log2(e)
#define NEGINF_ -1e30f

typedef short b16x8 __attribute__((ext_vector_type(8)));
typedef short b16x4 __attribute__((ext_vector_type(4)));
typedef float f32x4 __attribute__((ext_vector_type(4)));

#define MFMA16(a, b, c) __builtin_amdgcn_mfma_f32_16x16x32_bf16(a, b, c, 0, 0, 0)
#define MFMA16K16(a, b, c) __builtin_amdgcn_mfma_f32_16x16x16bf16_1k(a, b, c, 0, 0, 0)

#define GLL16(gp, lp) \
    __builtin_amdgcn_global_load_lds((const __attribute__((address_space(1))) void*)(gp), \
                                     (__attribute__((address_space(3))) void*)(lp), 16, 0, 0)

#if __has_builtin(__builtin_amdgcn_exp2f)
#define EXP2F(x) __builtin_amdgcn_exp2f(x)
#else
#define EXP2F(x) exp2f(x)
#endif

// fp32 -> bf16 RNE (finite inputs)
static __device__ inline short f2bf(float f) {
    unsigned int u = __builtin_bit_cast(unsigned int, f);
    unsigned int r = (u + 0x7fffu + ((u >> 16) & 1u)) >> 16;
    return (short)r;
}
// fp32 -> bf16 truncation (1 VALU op; used for P where bias is negligible)
static __device__ inline short f2bf_trunc(float f) {
    return (short)(__builtin_bit_cast(unsigned int, f) >> 16);
}
// bf16 -> fp32
static __device__ inline float bf2f(short s) {
    return __builtin_bit_cast(float, ((unsigned int)(unsigned short)s) << 16);
}

// ---------------------------------------------------------------------------
// Prologue: weight transposes (blocks 0..3071) + LN1 of x (blocks 3072..5119).
// block (32,8) = 256 threads.
// ---------------------------------------------------------------------------
__global__ __launch_bounds__(256) void prologue_kernel(
        const float* __restrict__ Wq, const float* __restrict__ Wk,
        const float* __restrict__ Wv, const float* __restrict__ Wp,
        const float* __restrict__ W1, const float* __restrict__ W2,
        short* __restrict__ wqkv, short* __restrict__ wpt,
        short* __restrict__ w1t, short* __restrict__ w2t,
        const float* __restrict__ X, const float* __restrict__ G,
        const float* __restrict__ Bb, short* __restrict__ Y)
{
    __shared__ float tile[32][33];
    int idx = blockIdx.x;
    if (idx >= 3072) {
        // LayerNorm: 4 rows/block, one row per wave
        int tid = threadIdx.y * 32 + threadIdx.x;
        int wave = tid >> 6, t = tid & 63;
        int row = (idx - 3072) * 4 + wave;
        const float* xr = X + (size_t)row * D_;
        float4 v0 = *(const float4*)(xr + t * 4);
        float4 v1 = *(const float4*)(xr + 256 + t * 4);
        float sum = v0.x + v0.y + v0.z + v0.w + v1.x + v1.y + v1.z + v1.w;
        float ssq = v0.x*v0.x + v0.y*v0.y + v0.z*v0.z + v0.w*v0.w
                  + v1.x*v1.x + v1.y*v1.y + v1.z*v1.z + v1.w*v1.w;
        #pragma unroll
        for (int off = 32; off > 0; off >>= 1) {
            sum += __shfl_down(sum, off);
            ssq += __shfl_down(ssq, off);
        }
        sum = __shfl(sum, 0);
        ssq = __shfl(ssq, 0);
        float mean = sum * (1.0f / D_);
        float var  = ssq * (1.0f / D_) - mean * mean;
        float rstd = rsqrtf(var + EPS_);
        float4 g0 = *(const float4*)(G + t * 4);
        float4 g1 = *(const float4*)(G + 256 + t * 4);
        float4 b0 = *(const float4*)(Bb + t * 4);
        float4 b1 = *(const float4*)(Bb + 256 + t * 4);
        short4 o0, o1;
        o0.x = f2bf((v0.x - mean) * rstd * g0.x + b0.x);
        o0.y = f2bf((v0.y - mean) * rstd * g0.y + b0.y);
        o0.z = f2bf((v0.z - mean) * rstd * g0.z + b0.z);
        o0.w = f2bf((v0.w - mean) * rstd * g0.w + b0.w);
        o1.x = f2bf((v1.x - mean) * rstd * g1.x + b1.x);
        o1.y = f2bf((v1.y - mean) * rstd * g1.y + b1.y);
        o1.z = f2bf((v1.z - mean) * rstd * g1.z + b1.z);
        o1.w = f2bf((v1.w - mean) * rstd * g1.w + b1.w);
        short* yr = Y + (size_t)row * D_;
        *(short4*)(yr + t * 4)       = o0;
        *(short4*)(yr + 256 + t * 4) = o1;
        return;
    }
    const float* src; short* dst; int R, C, tx0, ty0;
    if (idx < 768) {            // Wq/Wk/Wv: per head [512][64] -> [64][512]
        int w = idx >> 8, rem = idx & 255;
        int hh = rem >> 5, t = rem & 31;
        const float* base = (w == 0) ? Wq : ((w == 1) ? Wk : Wv);
        src = base + hh * (D_ * DH_);
        dst = wqkv + w * (512 * 512) + hh * (DH_ * D_);
        R = 512; C = 64; tx0 = (t & 1) * 32; ty0 = (t >> 1) * 32;
    } else if (idx < 1024) {    // Wproj [512][512]
        int t = idx - 768;
        src = Wp; dst = wpt; R = 512; C = 512;
        tx0 = (t & 15) * 32; ty0 = (t >> 4) * 32;
    } else if (idx < 2048) {    // W1 [512][2048] -> [2048][512]
        int t = idx - 1024;
        src = W1; dst = w1t; R = 512; C = 2048;
        tx0 = (t & 63) * 32; ty0 = (t >> 6) * 32;
    } else {                    // W2 [2048][512] -> [512][2048]
        int t = idx - 2048;
        src = W2; dst = w2t; R = 2048; C = 512;
        tx0 = (t & 15) * 32; ty0 = (t >> 4) * 32;
    }
    int tx = threadIdx.x, ty = threadIdx.y;
    #pragma unroll
    for (int i = 0; i < 32; i += 8)
        tile[ty + i][tx] = src[(size_t)(ty0 + ty + i) * C + tx0 + tx];
    __syncthreads();
    #pragma unroll
    for (int i = 0; i < 32; i += 8)
        dst[(size_t)(tx0 + ty + i) * R + ty0 + tx] = f2bf(tile[tx][ty + i]);
}

// ---------------------------------------------------------------------------
// LayerNorm over bf16 input (x1 path): 4 rows/block, one row per wave.
// ---------------------------------------------------------------------------
__global__ __launch_bounds__(256) void ln_bf16_kernel(const short* __restrict__ X,
        const float* __restrict__ G, const float* __restrict__ Bb,
        short* __restrict__ Y)
{
    int wave = threadIdx.x >> 6, t = threadIdx.x & 63;
    int row = blockIdx.x * 4 + wave;
    const short* xr = X + (size_t)row * D_ + t * 8;
    b16x8 xv = *(const b16x8*)xr;
    float v[8];
    float sum = 0.0f, ssq = 0.0f;
    #pragma unroll
    for (int e = 0; e < 8; ++e) {
        v[e] = bf2f(xv[e]);
        sum += v[e];
        ssq += v[e] * v[e];
    }
    #pragma unroll
    for (int off = 32; off > 0; off >>= 1) {
        sum += __shfl_down(sum, off);
        ssq += __shfl_down(ssq, off);
    }
    sum = __shfl(sum, 0);
    ssq = __shfl(ssq, 0);
    float mean = sum * (1.0f / D_);
    float var  = ssq * (1.0f / D_) - mean * mean;
    float rstd = rsqrtf(var + EPS_);

    float4 g0 = *(const float4*)(G + t * 8);
    float4 g1 = *(const float4*)(G + t * 8 + 4);
    float4 b0 = *(const float4*)(Bb + t * 8);
    float4 b1 = *(const float4*)(Bb + t * 8 + 4);
    float gg[8] = {g0.x, g0.y, g0.z, g0.w, g1.x, g1.y, g1.z, g1.w};
    float bb[8] = {b0.x, b0.y, b0.z, b0.w, b1.x, b1.y, b1.z, b1.w};
    b16x8 o;
    #pragma unroll
    for (int e = 0; e < 8; ++e)
        o[e] = f2bf((v[e] - mean) * rstd * gg[e] + bb[e]);
    *(b16x8*)(Y + (size_t)row * D_ + t * 8) = o;
}

// ---------------------------------------------------------------------------
// bf16 MFMA GEMM, 256x256, BK=64, 512 threads / 8 waves (2M x 4N).
// 2-phase 256^2 geometry from verified parts (R7). 128 KB LDS -> 1 block/CU.
// ---------------------------------------------------------------------------
__global__ __launch_bounds__(512, 2) void mm256_kernel(const short* __restrict__ A,
        const short* __restrict__ Bt, void* __restrict__ C,
        const float* __restrict__ bias, int relu, int N, int K)
{
    __shared__ short As[2][256 * 64];   // 64 KB
    __shared__ short Bs[2][256 * 64];   // 64 KB
    const int tid = threadIdx.x;
    const int wave = tid >> 6, lane = tid & 63;
    const int quad = lane >> 4, l15 = lane & 15;
    const int m0 = blockIdx.x * 256, n0 = blockIdx.y * 256;
    const int mw = (wave & 1) * 128, nw = (wave >> 1) * 64;

#define STAGE_M256(bufi, kk) \
    { \
        for (int r = 0; r < 4; ++r) { \
            int c = r * 512 + tid; \
            int row = c >> 3, seg = (c & 7) ^ (row & 7); \
            GLL16(A + (size_t)(m0 + row) * K + (kk) + seg * 8, \
                  As[bufi] + (size_t)(r * 512 + wave * 64) * 8); \
            GLL16(Bt + (size_t)(n0 + row) * K + (kk) + seg * 8, \
                  Bs[bufi] + (size_t)(r * 512 + wave * 64) * 8); \
        } \
    }

    f32x4 acc[8][4];
    #pragma unroll
    for (int i = 0; i < 8; ++i)
        #pragma unroll
        for (int j = 0; j < 4; ++j)
            acc[i][j] = (f32x4){0.f, 0.f, 0.f, 0.f};

    const int NT = K >> 6;   // 8 for K=512
    STAGE_M256(0, 0);
    int buf = 0;
    for (int t = 0; t < NT; ++t) {
        __syncthreads();     // stage(buf) landed (vmcnt0 drain); prev reads done
        if (t + 1 < NT) STAGE_M256(buf ^ 1, (t + 1) * 64);
        #pragma unroll
        for (int kb = 0; kb < 2; ++kb) {
            b16x8 af[8], bf[4];
            #pragma unroll
            for (int i = 0; i < 8; ++i) {
                int row = mw + i * 16 + l15;
                af[i] = *(const b16x8*)(As[buf] + row * 64 + (((kb * 4 + quad) ^ (row & 7)) * 8));
            }
            #pragma unroll
            for (int j = 0; j < 4; ++j) {
                int row = nw + j * 16 + l15;
                bf[j] = *(const b16x8*)(Bs[buf] + row * 64 + (((kb * 4 + quad) ^ (row & 7)) * 8));
            }
            #pragma unroll
            for (int i = 0; i < 8; ++i)
                #pragma unroll
                for (int j = 0; j < 4; ++j)
                    acc[i][j] = MFMA16(af[i], bf[j], acc[i][j]);
        }
        buf ^= 1;
    }
#undef STAGE_M256

    #pragma unroll
    for (int i = 0; i < 8; ++i) {
        #pragma unroll
        for (int r = 0; r < 4; ++r) {
            size_t row = (size_t)(m0 + mw + i * 16 + quad * 4 + r);
            #pragma unroll
            for (int j = 0; j < 4; ++j) {
                int col = n0 + nw + j * 16 + l15;
                float v = acc[i][j][r];
                if (bias)  v += bias[col];
                if (relu)  v = fmaxf(v, 0.0f);
                ((short*)C)[row * N + col] = f2bf(v);
            }
        }
    }
}

// ---------------------------------------------------------------------------
// bf16 MFMA GEMM, 64x64, BK=64 dbuf pipeline (proj, FFN2). grid=(M/64, N/64).
// 32 KB LDS keeps 4 blk/CU. Chunk swizzle f(row)=row&7 (conflict-free).
// ---------------------------------------------------------------------------
__global__ __launch_bounds__(256) void mm6464_kernel(const short* __restrict__ A,
        const short* __restrict__ Bt, void* __restrict__ C,
        const float* __restrict__ bias, const void* __restrict__ resid,
        int M, int N, int K, int relu, int out_bf16, int resid_bf16)
{
    __shared__ short As[2][64 * 64];
    __shared__ short Bs[2][64 * 64];
    const int tid = threadIdx.x;
    const int wave = tid >> 6, lane = tid & 63;
    const int quad = lane >> 4, l15 = lane & 15;
    const int m0 = blockIdx.x * 64, n0 = blockIdx.y * 64;
    const int nw = wave * 16;

#define STAGE_M66(bufi, kk) \
    { \
        for (int r = 0; r < 2; ++r) { \
            int c = r * 256 + tid; \
            int row = c >> 3, seg = (c & 7) ^ (row & 7); \
            GLL16(A + (size_t)(m0 + row) * K + (kk) + seg * 8, \
                  As[bufi] + (size_t)(r * 256 + wave * 64) * 8); \
            GLL16(Bt + (size_t)(n0 + row) * K + (kk) + seg * 8, \
                  Bs[bufi] + (size_t)(r * 256 + wave * 64) * 8); \
        } \
    }

    f32x4 acc[4];
    #pragma unroll
    for (int i = 0; i < 4; ++i) acc[i] = (f32x4){0.f, 0.f, 0.f, 0.f};

    STAGE_M66(0, 0);
    int buf = 0;
    for (int k0 = 0; k0 < K; k0 += 64) {
        __syncthreads();
        if (k0 + 64 < K) STAGE_M66(buf ^ 1, k0 + 64);
        b16x8 af[4][2], bf[2];
        #pragma unroll
        for (int i = 0; i < 4; ++i)
            #pragma unroll
            for (int kb = 0; kb < 2; ++kb) {
                int row = i * 16 + l15;
                af[i][kb] = *(const b16x8*)(As[buf] + row * 64 + (((kb * 4 + quad) ^ (row & 7)) * 8));
            }
        #pragma unroll
        for (int kb = 0; kb < 2; ++kb) {
            int row = nw + l15;
            bf[kb] = *(const b16x8*)(Bs[buf] + row * 64 + (((kb * 4 + quad) ^ (row & 7)) * 8));
        }
        #pragma unroll
        for (int kb = 0; kb < 2; ++kb)
            #pragma unroll
            for (int i = 0; i < 4; ++i)
                acc[i] = MFMA16(af[i][kb], bf[kb], acc[i]);
        buf ^= 1;
    }
#undef STAGE_M66

    #pragma unroll
    for (int i = 0; i < 4; ++i) {
        #pragma unroll
        for (int r = 0; r < 4; ++r) {
            size_t row = (size_t)(m0 + i * 16 + quad * 4 + r);
            int col = n0 + nw + l15;
            float v = acc[i][r];
            if (bias)  v += bias[col];
            if (resid) {
                if (resid_bf16) v += bf2f(((const short*)resid)[row * N + col]);
                else            v += ((const float*)resid)[row * N + col];
            }
            if (relu)  v = fmaxf(v, 0.0f);
            if (out_bf16) ((short*)C)[row * N + col] = f2bf(v);
            else          ((float*)C)[row * N + col] = v;
        }
    }
}

// ---------------------------------------------------------------------------
// Flash attention, S^T formulation, STATIC-MAX softmax (m == 0).
// R11: R0 per-tile body VERBATIM (proven fastest: R1 dbuf / R3 destage /
// R10 QBLK=128 all regressed -- the kernel is TLP-bound). One change:
// SPLIT-K x4 (was x2). Max block length 16 -> 8 tiles, halving the dispatch
// tail that capped measured occupancy at 32% of the 75% nominal (6 blk/CU).
// grid (32 bh, 32 qt, 4 split) = 4096 blocks. Split s covers tiles
// [s*(qi+1)/4, (s+1)*(qi+1)/4); empty splits zero-fill; split 3 always
// holds the diagonal so every row's total mass > 0.
// ---------------------------------------------------------------------------
__global__ __launch_bounds__(256) void attn_kernel(const short* __restrict__ qkv,
        short* __restrict__ Opart, float* __restrict__ Ml)
{
    __shared__ short Qs[64 * 72];   // [0..64*64): swizzled Q; epilogue: stride-72 repack
    __shared__ short Ks[64 * 64];   // [tok][dh], swizzled
    __shared__ short Vt[64 * 64];   // [dh][tok], granule-swizzled, stride 64

    const int tid = threadIdx.x;
    const int wave = tid >> 6, lane = tid & 63;
    const int quad = lane >> 4, l15 = lane & 15;
    const int bh = blockIdx.x;
    const int qi = 31 - (int)blockIdx.y;
    const int split = blockIdx.z;
    const int b = bh >> 3, h = bh & 7;
    const size_t tok0 = (size_t)b * T_;
    const int qrow_rel = wave * 16 + l15;
    const int tot = qi + 1;
    const int klo = (split * tot) >> 2;
    const int khi = ((split + 1) * tot) >> 2;
    const int pidx = split * 1024 + bh * 32 + qi;
    short* Op = Opart + (size_t)pidx * 4096;
    float* mlp = Ml + (size_t)pidx * 64;

    if (klo >= khi) {               // empty split (small qi)
        for (int i = tid; i < 2048; i += 256) ((int*)Op)[i] = 0;
        if (tid < 64) mlp[tid] = 0.0f;
        return;
    }

    // stage Q tile (swizzled)
    #pragma unroll
    for (int r = 0; r < 2; ++r) {
        int c = r * 256 + tid;
        int tk = c >> 3;
        int seg = (c & 7) ^ (tk & 7);
        GLL16(qkv + (tok0 + qi * 64 + tk) * 1536 + h * 64 + seg * 8,
              Qs + (size_t)(r * 256 + wave * 64) * 8);
    }

    float lrow = 0.0f;
    f32x4 ot[4];   // O^T: row=dh=dt*16+quad*4+rr, col=qrow=l15
    #pragma unroll
    for (int dt = 0; dt < 4; ++dt) ot[dt] = (f32x4){0.f, 0.f, 0.f, 0.f};

    b16x8 qf[2];

    for (int kj = klo; kj < khi; ++kj) {
        __syncthreads();   // prev-iter LDS reads done (and Q GLL drained on first)
        // stage K tile (swizzled)
        #pragma unroll
        for (int r = 0; r < 2; ++r) {
            int c = r * 256 + tid;
            int tk = c >> 3;
            int seg = (c & 7) ^ (tk & 7);
            GLL16(qkv + (tok0 + kj * 64 + tk) * 1536 + 512 + h * 64 + seg * 8,
                  Ks + (size_t)(r * 256 + wave * 64) * 8);
        }
        // stage V transposed, granule-swizzled: thread = (s 0..7, tp 0..31)
        {
            int s = tid >> 5, tp = tid & 31;
            const short* g0 = qkv + (tok0 + kj * 64 + tp * 2) * 1536 + 1024 + h * 64 + s * 8;
            b16x8 v0 = *(const b16x8*)g0;
            b16x8 v1 = *(const b16x8*)(g0 + 1536);
            int* vo = (int*)Vt;
            int gg = tp >> 1, hlf = tp & 1;
            #pragma unroll
            for (int e = 0; e < 8; ++e) {
                int row = s * 8 + e;
                unsigned int pk = (unsigned int)(unsigned short)v0[e]
                                | ((unsigned int)(unsigned short)v1[e] << 16);
                vo[row * 32 + ((gg ^ (row & 15)) << 1) + hlf] = pk;
            }
        }
        __syncthreads();

        if (kj == klo) {   // Q fragment (B-operand: n=l15=qrow, k=quad*8+j), hoisted
            #pragma unroll
            for (int kb = 0; kb < 2; ++kb) {
                int row = wave * 16 + l15;
                qf[kb] = *(const b16x8*)(Qs + row * 64 + (((kb * 4 + quad) ^ (row & 7)) * 8));
            }
        }

        // S^T = K Q^T  (A=K-frag, B=Q-frag)
        f32x4 st[4];   // mt token-tiles: token = mt*16+quad*4+r, qrow = l15
        #pragma unroll
        for (int mt = 0; mt < 4; ++mt) st[mt] = (f32x4){0.f, 0.f, 0.f, 0.f};
        #pragma unroll
        for (int mt = 0; mt < 4; ++mt) {
            int trow = mt * 16 + l15;
            #pragma unroll
            for (int kb = 0; kb < 2; ++kb) {
                b16x8 kf = *(const b16x8*)(Ks + trow * 64 + (((kb * 4 + quad) ^ (trow & 7)) * 8));
                st[mt] = MFMA16(kf, qf[kb], st[mt]);
            }
        }

        // causal mask + P = exp2(S*SC2) (no max subtraction)
        const bool diag = (kj == qi);
        float rs = 0.0f;
        b16x4 pf[4];   // P^T fragments: directly in 16x16x16 B-operand layout
        #pragma unroll
        for (int mt = 0; mt < 4; ++mt)
            #pragma unroll
            for (int r = 0; r < 4; ++r) {
                float s = st[mt][r];
                if (diag && (mt * 16 + quad * 4 + r) > qrow_rel) s = NEGINF_;
                float e = EXP2F(s * SC2_);
                rs += e;
                pf[mt][r] = f2bf_trunc(e);
            }
        rs += __shfl_xor(rs, 16);
        rs += __shfl_xor(rs, 32);
        lrow += rs;
        // O^T += V^T P^T  (16x16x16; A=V^T-frag from swizzled Vt, B=P^T in regs)
        #pragma unroll
        for (int dt = 0; dt < 4; ++dt) {
            const short* vrow = Vt + (dt * 16 + l15) * 64;
            #pragma unroll
            for (int kt = 0; kt < 4; ++kt) {
                b16x4 vf = *(const b16x4*)(vrow + (((kt * 4 + quad) ^ l15) << 2));
                ot[dt] = MFMA16K16(vf, pf[kt], ot[dt]);
            }
        }
    }

    // epilogue: normalize, repack via same-wave LDS strip (Qs alias), store
    __syncthreads();   // all waves done reading Ks/Vt AND Qs fragments
    float inv = (lrow > 0.0f) ? 1.0f / lrow : 0.0f;   // guard (vacuous here, safe)
    #pragma unroll
    for (int dt = 0; dt < 4; ++dt) {
        b16x4 o4;
        o4[0] = f2bf(ot[dt][0] * inv);
        o4[1] = f2bf(ot[dt][1] * inv);
        o4[2] = f2bf(ot[dt][2] * inv);
        o4[3] = f2bf(ot[dt][3] * inv);
        *(b16x4*)(Qs + (size_t)qrow_rel * 72 + dt * 16 + quad * 4) = o4;
    }
    // rows tid>>2 land inside this wave's own strip -> DS in-order, no barrier
    {
        int row = tid >> 2, ch = tid & 3;
        b16x8 lo = *(const b16x8*)(Qs + (size_t)row * 72 + ch * 16);
        b16x8 hi = *(const b16x8*)(Qs + (size_t)row * 72 + ch * 16 + 8);
        short* dst = Op + row * 64 + ch * 16;
        *(b16x8*)dst = lo;
        *(b16x8*)(dst + 8) = hi;
    }
    if (quad == 0) mlp[qrow_rel] = lrow;
}

// ---------------------------------------------------------------------------
// Combine the four attn split-K partials: O = (Σ l_s O_s) / (Σ l_s).
// grid 1024 (one (bh,qi) per block), 256 threads. Σ l_s > 0 always
// (split 3 is nonempty and contains the diagonal for every row).
// ---------------------------------------------------------------------------
__global__ __launch_bounds__(256) void attn_combine_kernel(
        const short* __restrict__ Opart, const float* __restrict__ Ml,
        short* __restrict__ Ob)
{
    int pair = blockIdx.x;              // bh*32 + qi
    int bh = pair >> 5, qi = pair & 31;
    int b = bh >> 3, h = bh & 7;
    int tid = threadIdx.x;
    int ch = tid & 7;                   // 8 shorts per chunk
    #pragma unroll
    for (int it = 0; it < 2; ++it) {
        int row = it * 32 + (tid >> 3);
        float l[4], lsum = 0.0f;
        #pragma unroll
        for (int s = 0; s < 4; ++s) {
            l[s] = Ml[(size_t)(s * 1024 + pair) * 64 + row];
            lsum += l[s];
        }
        float inv = 1.0f / lsum;
        float acc[8] = {0.f, 0.f, 0.f, 0.f, 0.f, 0.f, 0.f, 0.f};
        #pragma unroll
        for (int s = 0; s < 4; ++s) {
            float w = l[s] * inv;
            b16x8 a = *(const b16x8*)(Opart + (size_t)(s * 1024 + pair) * 4096
                                      + row * 64 + ch * 8);
            #pragma unroll
            for (int e = 0; e < 8; ++e)
                acc[e] += w * bf2f(a[e]);
        }
        b16x8 o;
        #pragma unroll
        for (int e = 0; e < 8; ++e) o[e] = f2bf(acc[e]);
        short* dst = Ob + ((size_t)(b * T_ + qi * 64 + row)) * 512 + h * 64 + ch * 8;
        *(b16x8*)dst = o;
    }
}

// ---------------------------------------------------------------------------
extern "C" void kernel_launch(void* const* d_in, const int* in_sizes, int n_in,
                              void* d_out, int out_size, void* d_ws, size_t ws_size,
                              hipStream_t stream) {
    (void)in_sizes; (void)n_in; (void)out_size; (void)ws_size;
    const float* x     = (const float*)d_in[0];
    const float* ln_g  = (const float*)d_in[1];
    const float* ln_b  = (const float*)d_in[2];
    const float* Wq    = (const float*)d_in[3];
    const float* Wk    = (const float*)d_in[4];
    const float* Wv    = (const float*)d_in[5];
    const float* Wproj = (const float*)d_in[6];
    const float* bproj = (const float*)d_in[7];
    const float* W1    = (const float*)d_in[8];
    const float* b1    = (const float*)d_in[9];
    const float* W2    = (const float*)d_in[10];
    const float* b2    = (const float*)d_in[11];
    float* out = (float*)d_out;

    char* W = (char*)d_ws;
    short* hbuf  = (short*)(W + 0);                    // 8 MB  (LN out, bf16)
    short* qkvb  = (short*)(W + ((size_t)8  << 20));   // 24 MB [BT][1536]
    short* attno = (short*)(W + ((size_t)32 << 20));   // 8 MB  [BT][512]
    short* x1b   = (short*)(W + ((size_t)40 << 20));   // 8 MB  [BT][512] bf16
    short* ff1   = (short*)(W + ((size_t)56 << 20));   // 32 MB [BT][2048]
    // Opart (32 MB, [4][1024][64][64] bf16) ALIASES ff1: attn+combine complete
    // before step 5 writes ff1. Ml (1 MB, [4][1024][64] f32) ALIASES wqkv:
    // wqkv is dead after step 1 (QKV GEMM), attn runs after.
    short* Opart = ff1;
    short* wqkv  = (short*)(W + ((size_t)88 << 20));   // 1.5 MB [1536][512]
    float* Ml    = (float*)(W + ((size_t)88 << 20));   // 1 MB (aliases wqkv)
    short* wpt   = (short*)(W + ((size_t)90 << 20));   // 0.5 MB [512][512]
    short* w1t   = (short*)(W + ((size_t)91 << 20));   // 2 MB  [2048][512]
    short* w2t   = (short*)(W + ((size_t)93 << 20));   // 2 MB  [512][2048]

    // 0. weight transposes + LN1 fused in one launch
    prologue_kernel<<<dim3(3072 + BT_ / 4), dim3(32, 8), 0, stream>>>(
        Wq, Wk, Wv, Wproj, W1, W2, wqkv, wpt, w1t, w2t,
        x, ln_g, ln_b, hbuf);
    // 1. qkv = h @ Wqkv  [8192,1536] bf16  (256x256 tiles -> 192 blocks)
    mm256_kernel<<<dim3(32, 6), dim3(512), 0, stream>>>(hbuf, wqkv, qkvb,
        nullptr, 0, 1536, D_);
    // 2. attention split-K x4 -> partials, then combine -> attno bf16
    attn_kernel<<<dim3(32, 32, 4), dim3(256), 0, stream>>>(qkvb, Opart, Ml);
    attn_combine_kernel<<<dim3(1024), dim3(256), 0, stream>>>(Opart, Ml, attno);
    // 3. x1b = bf16(x + attno @ Wproj + bproj)   (BK=64 -> 16 iters)
    mm6464_kernel<<<dim3(128, 8), dim3(256), 0, stream>>>(attno, wpt, x1b,
        bproj, x, BT_, D_, D_, 0, 1, 0);
    // 4. h2 = LN(x1b) -> bf16 (reuse hbuf)
    ln_bf16_kernel<<<dim3(BT_ / 4), dim3(256), 0, stream>>>(x1b, ln_g, ln_b, hbuf);
    // 5. ff1 = relu(h2 @ W1 + b1)  bf16  (256x256 tiles -> 256 blocks = 1/CU)
    mm256_kernel<<<dim3(32, 8), dim3(512), 0, stream>>>(hbuf, w1t, ff1,
        b1, 1, FF_, D_);
    // 6. out = x1b + ff1 @ W2 + b2  (fp32 out, bf16 resid, BK=64 -> 32 iters)
    mm6464_kernel<<<dim3(128, 8), dim3(256), 0, stream>>>(ff1, w2t, out,
        b2, x1b, BT_, D_, FF_, 0, 0, 1);
}

// Round 12
// 250.961 us; speedup vs baseline: 1.0345x; 1.0215x over previous
//
#include <hip/hip_runtime.h>
#include <math.h>

#define B_ 4
#define T_ 2048
#define D_ 512
#define H_ 8
#define DH_ 64
#define BT_ 8192
#define FF_ 2048
#define EPS_ 1e-5f
#define SCALE_ 0.04419417382415922f   // 512^-0.5
#define SC2_ 0.06375861151f           // SCALE_ * log2(e)
#define NEGINF_ -1e30f

typedef short b16x8 __attribute__((ext_vector_type(8)));
typedef short b16x4 __attribute__((ext_vector_type(4)));
typedef float f32x4 __attribute__((ext_vector_type(4)));

#define MFMA16(a, b, c) __builtin_amdgcn_mfma_f32_16x16x32_bf16(a, b, c, 0, 0, 0)
#define MFMA16K16(a, b, c) __builtin_amdgcn_mfma_f32_16x16x16bf16_1k(a, b, c, 0, 0, 0)

#define GLL16(gp, lp) \
    __builtin_amdgcn_global_load_lds((const __attribute__((address_space(1))) void*)(gp), \
                                     (__attribute__((address_space(3))) void*)(lp), 16, 0, 0)

#if __has_builtin(__builtin_amdgcn_exp2f)
#define EXP2F(x) __builtin_amdgcn_exp2f(x)
#else
#define EXP2F(x) exp2f(x)
#endif

// fp32 -> bf16 RNE (finite inputs)
static __device__ inline short f2bf(float f) {
    unsigned int u = __builtin_bit_cast(unsigned int, f);
    unsigned int r = (u + 0x7fffu + ((u >> 16) & 1u)) >> 16;
    return (short)r;
}
// fp32 -> bf16 truncation (1 VALU op; used for P where bias is negligible)
static __device__ inline short f2bf_trunc(float f) {
    return (short)(__builtin_bit_cast(unsigned int, f) >> 16);
}
// bf16 -> fp32
static __device__ inline float bf2f(short s) {
    return __builtin_bit_cast(float, ((unsigned int)(unsigned short)s) << 16);
}

// ---------------------------------------------------------------------------
// Prologue: weight transposes (blocks 0..3071) + LN1 of x (blocks 3072..5119).
// block (32,8) = 256 threads.
// ---------------------------------------------------------------------------
__global__ __launch_bounds__(256) void prologue_kernel(
        const float* __restrict__ Wq, const float* __restrict__ Wk,
        const float* __restrict__ Wv, const float* __restrict__ Wp,
        const float* __restrict__ W1, const float* __restrict__ W2,
        short* __restrict__ wqkv, short* __restrict__ wpt,
        short* __restrict__ w1t, short* __restrict__ w2t,
        const float* __restrict__ X, const float* __restrict__ G,
        const float* __restrict__ Bb, short* __restrict__ Y)
{
    __shared__ float tile[32][33];
    int idx = blockIdx.x;
    if (idx >= 3072) {
        // LayerNorm: 4 rows/block, one row per wave
        int tid = threadIdx.y * 32 + threadIdx.x;
        int wave = tid >> 6, t = tid & 63;
        int row = (idx - 3072) * 4 + wave;
        const float* xr = X + (size_t)row * D_;
        float4 v0 = *(const float4*)(xr + t * 4);
        float4 v1 = *(const float4*)(xr + 256 + t * 4);
        float sum = v0.x + v0.y + v0.z + v0.w + v1.x + v1.y + v1.z + v1.w;
        float ssq = v0.x*v0.x + v0.y*v0.y + v0.z*v0.z + v0.w*v0.w
                  + v1.x*v1.x + v1.y*v1.y + v1.z*v1.z + v1.w*v1.w;
        #pragma unroll
        for (int off = 32; off > 0; off >>= 1) {
            sum += __shfl_down(sum, off);
            ssq += __shfl_down(ssq, off);
        }
        sum = __shfl(sum, 0);
        ssq = __shfl(ssq, 0);
        float mean = sum * (1.0f / D_);
        float var  = ssq * (1.0f / D_) - mean * mean;
        float rstd = rsqrtf(var + EPS_);
        float4 g0 = *(const float4*)(G + t * 4);
        float4 g1 = *(const float4*)(G + 256 + t * 4);
        float4 b0 = *(const float4*)(Bb + t * 4);
        float4 b1 = *(const float4*)(Bb + 256 + t * 4);
        short4 o0, o1;
        o0.x = f2bf((v0.x - mean) * rstd * g0.x + b0.x);
        o0.y = f2bf((v0.y - mean) * rstd * g0.y + b0.y);
        o0.z = f2bf((v0.z - mean) * rstd * g0.z + b0.z);
        o0.w = f2bf((v0.w - mean) * rstd * g0.w + b0.w);
        o1.x = f2bf((v1.x - mean) * rstd * g1.x + b1.x);
        o1.y = f2bf((v1.y - mean) * rstd * g1.y + b1.y);
        o1.z = f2bf((v1.z - mean) * rstd * g1.z + b1.z);
        o1.w = f2bf((v1.w - mean) * rstd * g1.w + b1.w);
        short* yr = Y + (size_t)row * D_;
        *(short4*)(yr + t * 4)       = o0;
        *(short4*)(yr + 256 + t * 4) = o1;
        return;
    }
    const float* src; short* dst; int R, C, tx0, ty0;
    if (idx < 768) {            // Wq/Wk/Wv: per head [512][64] -> [64][512]
        int w = idx >> 8, rem = idx & 255;
        int hh = rem >> 5, t = rem & 31;
        const float* base = (w == 0) ? Wq : ((w == 1) ? Wk : Wv);
        src = base + hh * (D_ * DH_);
        dst = wqkv + w * (512 * 512) + hh * (DH_ * D_);
        R = 512; C = 64; tx0 = (t & 1) * 32; ty0 = (t >> 1) * 32;
    } else if (idx < 1024) {    // Wproj [512][512]
        int t = idx - 768;
        src = Wp; dst = wpt; R = 512; C = 512;
        tx0 = (t & 15) * 32; ty0 = (t >> 4) * 32;
    } else if (idx < 2048) {    // W1 [512][2048] -> [2048][512]
        int t = idx - 1024;
        src = W1; dst = w1t; R = 512; C = 2048;
        tx0 = (t & 63) * 32; ty0 = (t >> 6) * 32;
    } else {                    // W2 [2048][512] -> [512][2048]
        int t = idx - 2048;
        src = W2; dst = w2t; R = 2048; C = 512;
        tx0 = (t & 15) * 32; ty0 = (t >> 4) * 32;
    }
    int tx = threadIdx.x, ty = threadIdx.y;
    #pragma unroll
    for (int i = 0; i < 32; i += 8)
        tile[ty + i][tx] = src[(size_t)(ty0 + ty + i) * C + tx0 + tx];
    __syncthreads();
    #pragma unroll
    for (int i = 0; i < 32; i += 8)
        dst[(size_t)(tx0 + ty + i) * R + ty0 + tx] = f2bf(tile[tx][ty + i]);
}

// ---------------------------------------------------------------------------
// LayerNorm over bf16 input (x1 path): 4 rows/block, one row per wave.
// ---------------------------------------------------------------------------
__global__ __launch_bounds__(256) void ln_bf16_kernel(const short* __restrict__ X,
        const float* __restrict__ G, const float* __restrict__ Bb,
        short* __restrict__ Y)
{
    int wave = threadIdx.x >> 6, t = threadIdx.x & 63;
    int row = blockIdx.x * 4 + wave;
    const short* xr = X + (size_t)row * D_ + t * 8;
    b16x8 xv = *(const b16x8*)xr;
    float v[8];
    float sum = 0.0f, ssq = 0.0f;
    #pragma unroll
    for (int e = 0; e < 8; ++e) {
        v[e] = bf2f(xv[e]);
        sum += v[e];
        ssq += v[e] * v[e];
    }
    #pragma unroll
    for (int off = 32; off > 0; off >>= 1) {
        sum += __shfl_down(sum, off);
        ssq += __shfl_down(ssq, off);
    }
    sum = __shfl(sum, 0);
    ssq = __shfl(ssq, 0);
    float mean = sum * (1.0f / D_);
    float var  = ssq * (1.0f / D_) - mean * mean;
    float rstd = rsqrtf(var + EPS_);

    float4 g0 = *(const float4*)(G + t * 8);
    float4 g1 = *(const float4*)(G + t * 8 + 4);
    float4 b0 = *(const float4*)(Bb + t * 8);
    float4 b1 = *(const float4*)(Bb + t * 8 + 4);
    float gg[8] = {g0.x, g0.y, g0.z, g0.w, g1.x, g1.y, g1.z, g1.w};
    float bb[8] = {b0.x, b0.y, b0.z, b0.w, b1.x, b1.y, b1.z, b1.w};
    b16x8 o;
    #pragma unroll
    for (int e = 0; e < 8; ++e)
        o[e] = f2bf((v[e] - mean) * rstd * gg[e] + bb[e]);
    *(b16x8*)(Y + (size_t)row * D_ + t * 8) = o;
}

// ---------------------------------------------------------------------------
// bf16 MFMA GEMM, 256x256, BK=64, 512 threads / 8 waves (2M x 4N).
// 2-phase 256^2 geometry from verified parts (R7). 128 KB LDS -> 1 block/CU.
// ---------------------------------------------------------------------------
__global__ __launch_bounds__(512, 2) void mm256_kernel(const short* __restrict__ A,
        const short* __restrict__ Bt, void* __restrict__ C,
        const float* __restrict__ bias, int relu, int N, int K)
{
    __shared__ short As[2][256 * 64];   // 64 KB
    __shared__ short Bs[2][256 * 64];   // 64 KB
    const int tid = threadIdx.x;
    const int wave = tid >> 6, lane = tid & 63;
    const int quad = lane >> 4, l15 = lane & 15;
    const int m0 = blockIdx.x * 256, n0 = blockIdx.y * 256;
    const int mw = (wave & 1) * 128, nw = (wave >> 1) * 64;

#define STAGE_M256(bufi, kk) \
    { \
        for (int r = 0; r < 4; ++r) { \
            int c = r * 512 + tid; \
            int row = c >> 3, seg = (c & 7) ^ (row & 7); \
            GLL16(A + (size_t)(m0 + row) * K + (kk) + seg * 8, \
                  As[bufi] + (size_t)(r * 512 + wave * 64) * 8); \
            GLL16(Bt + (size_t)(n0 + row) * K + (kk) + seg * 8, \
                  Bs[bufi] + (size_t)(r * 512 + wave * 64) * 8); \
        } \
    }

    f32x4 acc[8][4];
    #pragma unroll
    for (int i = 0; i < 8; ++i)
        #pragma unroll
        for (int j = 0; j < 4; ++j)
            acc[i][j] = (f32x4){0.f, 0.f, 0.f, 0.f};

    const int NT = K >> 6;   // 8 for K=512
    STAGE_M256(0, 0);
    int buf = 0;
    for (int t = 0; t < NT; ++t) {
        __syncthreads();     // stage(buf) landed (vmcnt0 drain); prev reads done
        if (t + 1 < NT) STAGE_M256(buf ^ 1, (t + 1) * 64);
        #pragma unroll
        for (int kb = 0; kb < 2; ++kb) {
            b16x8 af[8], bf[4];
            #pragma unroll
            for (int i = 0; i < 8; ++i) {
                int row = mw + i * 16 + l15;
                af[i] = *(const b16x8*)(As[buf] + row * 64 + (((kb * 4 + quad) ^ (row & 7)) * 8));
            }
            #pragma unroll
            for (int j = 0; j < 4; ++j) {
                int row = nw + j * 16 + l15;
                bf[j] = *(const b16x8*)(Bs[buf] + row * 64 + (((kb * 4 + quad) ^ (row & 7)) * 8));
            }
            #pragma unroll
            for (int i = 0; i < 8; ++i)
                #pragma unroll
                for (int j = 0; j < 4; ++j)
                    acc[i][j] = MFMA16(af[i], bf[j], acc[i][j]);
        }
        buf ^= 1;
    }
#undef STAGE_M256

    #pragma unroll
    for (int i = 0; i < 8; ++i) {
        #pragma unroll
        for (int r = 0; r < 4; ++r) {
            size_t row = (size_t)(m0 + mw + i * 16 + quad * 4 + r);
            #pragma unroll
            for (int j = 0; j < 4; ++j) {
                int col = n0 + nw + j * 16 + l15;
                float v = acc[i][j][r];
                if (bias)  v += bias[col];
                if (relu)  v = fmaxf(v, 0.0f);
                ((short*)C)[row * N + col] = f2bf(v);
            }
        }
    }
}

// ---------------------------------------------------------------------------
// bf16 MFMA GEMM, 64x64, BK=64 dbuf pipeline (proj, FFN2). grid=(M/64, N/64).
// 32 KB LDS keeps 4 blk/CU. Chunk swizzle f(row)=row&7 (conflict-free).
// ---------------------------------------------------------------------------
__global__ __launch_bounds__(256) void mm6464_kernel(const short* __restrict__ A,
        const short* __restrict__ Bt, void* __restrict__ C,
        const float* __restrict__ bias, const void* __restrict__ resid,
        int M, int N, int K, int relu, int out_bf16, int resid_bf16)
{
    __shared__ short As[2][64 * 64];
    __shared__ short Bs[2][64 * 64];
    const int tid = threadIdx.x;
    const int wave = tid >> 6, lane = tid & 63;
    const int quad = lane >> 4, l15 = lane & 15;
    const int m0 = blockIdx.x * 64, n0 = blockIdx.y * 64;
    const int nw = wave * 16;

#define STAGE_M66(bufi, kk) \
    { \
        for (int r = 0; r < 2; ++r) { \
            int c = r * 256 + tid; \
            int row = c >> 3, seg = (c & 7) ^ (row & 7); \
            GLL16(A + (size_t)(m0 + row) * K + (kk) + seg * 8, \
                  As[bufi] + (size_t)(r * 256 + wave * 64) * 8); \
            GLL16(Bt + (size_t)(n0 + row) * K + (kk) + seg * 8, \
                  Bs[bufi] + (size_t)(r * 256 + wave * 64) * 8); \
        } \
    }

    f32x4 acc[4];
    #pragma unroll
    for (int i = 0; i < 4; ++i) acc[i] = (f32x4){0.f, 0.f, 0.f, 0.f};

    STAGE_M66(0, 0);
    int buf = 0;
    for (int k0 = 0; k0 < K; k0 += 64) {
        __syncthreads();
        if (k0 + 64 < K) STAGE_M66(buf ^ 1, k0 + 64);
        b16x8 af[4][2], bf[2];
        #pragma unroll
        for (int i = 0; i < 4; ++i)
            #pragma unroll
            for (int kb = 0; kb < 2; ++kb) {
                int row = i * 16 + l15;
                af[i][kb] = *(const b16x8*)(As[buf] + row * 64 + (((kb * 4 + quad) ^ (row & 7)) * 8));
            }
        #pragma unroll
        for (int kb = 0; kb < 2; ++kb) {
            int row = nw + l15;
            bf[kb] = *(const b16x8*)(Bs[buf] + row * 64 + (((kb * 4 + quad) ^ (row & 7)) * 8));
        }
        #pragma unroll
        for (int kb = 0; kb < 2; ++kb)
            #pragma unroll
            for (int i = 0; i < 4; ++i)
                acc[i] = MFMA16(af[i][kb], bf[kb], acc[i]);
        buf ^= 1;
    }
#undef STAGE_M66

    #pragma unroll
    for (int i = 0; i < 4; ++i) {
        #pragma unroll
        for (int r = 0; r < 4; ++r) {
            size_t row = (size_t)(m0 + i * 16 + quad * 4 + r);
            int col = n0 + nw + l15;
            float v = acc[i][r];
            if (bias)  v += bias[col];
            if (resid) {
                if (resid_bf16) v += bf2f(((const short*)resid)[row * N + col]);
                else            v += ((const float*)resid)[row * N + col];
            }
            if (relu)  v = fmaxf(v, 0.0f);
            if (out_bf16) ((short*)C)[row * N + col] = f2bf(v);
            else          ((float*)C)[row * N + col] = v;
        }
    }
}

// ---------------------------------------------------------------------------
// Flash attention, S^T formulation, SPLIT-K x2, STATIC-MAX softmax (m == 0).
// grid (32 bh, 32 qt, 2 split). 25.6 KB LDS, 6 blocks/CU.
// (R0 structure verbatim -- measured optimum across R1 dbuf / R3 destage /
// R10 QBLK=128 / R11 split-K x4, all of which regressed. TLP-bound.)
// ---------------------------------------------------------------------------
__global__ __launch_bounds__(256) void attn_kernel(const short* __restrict__ qkv,
        short* __restrict__ Opart, float* __restrict__ Ml)
{
    __shared__ short Qs[64 * 72];   // [0..64*64): swizzled Q; epilogue: stride-72 repack
    __shared__ short Ks[64 * 64];   // [tok][dh], swizzled
    __shared__ short Vt[64 * 64];   // [dh][tok], granule-swizzled, stride 64

    const int tid = threadIdx.x;
    const int wave = tid >> 6, lane = tid & 63;
    const int quad = lane >> 4, l15 = lane & 15;
    const int bh = blockIdx.x;
    const int qi = 31 - (int)blockIdx.y;
    const int split = blockIdx.z;
    const int b = bh >> 3, h = bh & 7;
    const size_t tok0 = (size_t)b * T_;
    const int qrow_rel = wave * 16 + l15;
    const int half = (qi + 1) >> 1;
    const int klo = split ? half : 0;
    const int khi = split ? qi + 1 : half;
    const int pidx = split * 1024 + bh * 32 + qi;
    short* Op = Opart + (size_t)pidx * 4096;
    float* mlp = Ml + (size_t)pidx * 64;

    if (klo >= khi) {               // empty split (qi==0, split==0)
        for (int i = tid; i < 2048; i += 256) ((int*)Op)[i] = 0;
        if (tid < 64) mlp[tid] = 0.0f;
        return;
    }

    // stage Q tile (swizzled)
    #pragma unroll
    for (int r = 0; r < 2; ++r) {
        int c = r * 256 + tid;
        int tk = c >> 3;
        int seg = (c & 7) ^ (tk & 7);
        GLL16(qkv + (tok0 + qi * 64 + tk) * 1536 + h * 64 + seg * 8,
              Qs + (size_t)(r * 256 + wave * 64) * 8);
    }

    float lrow = 0.0f;
    f32x4 ot[4];   // O^T: row=dh=dt*16+quad*4+rr, col=qrow=l15
    #pragma unroll
    for (int dt = 0; dt < 4; ++dt) ot[dt] = (f32x4){0.f, 0.f, 0.f, 0.f};

    b16x8 qf[2];

    for (int kj = klo; kj < khi; ++kj) {
        __syncthreads();   // prev-iter LDS reads done (and Q GLL drained on first)
        // stage K tile (swizzled)
        #pragma unroll
        for (int r = 0; r < 2; ++r) {
            int c = r * 256 + tid;
            int tk = c >> 3;
            int seg = (c & 7) ^ (tk & 7);
            GLL16(qkv + (tok0 + kj * 64 + tk) * 1536 + 512 + h * 64 + seg * 8,
                  Ks + (size_t)(r * 256 + wave * 64) * 8);
        }
        // stage V transposed, granule-swizzled: thread = (s 0..7, tp 0..31)
        {
            int s = tid >> 5, tp = tid & 31;
            const short* g0 = qkv + (tok0 + kj * 64 + tp * 2) * 1536 + 1024 + h * 64 + s * 8;
            b16x8 v0 = *(const b16x8*)g0;
            b16x8 v1 = *(const b16x8*)(g0 + 1536);
            int* vo = (int*)Vt;
            int gg = tp >> 1, hlf = tp & 1;
            #pragma unroll
            for (int e = 0; e < 8; ++e) {
                int row = s * 8 + e;
                unsigned int pk = (unsigned int)(unsigned short)v0[e]
                                | ((unsigned int)(unsigned short)v1[e] << 16);
                vo[row * 32 + ((gg ^ (row & 15)) << 1) + hlf] = pk;
            }
        }
        __syncthreads();

        if (kj == klo) {   // Q fragment (B-operand: n=l15=qrow, k=quad*8+j), hoisted
            #pragma unroll
            for (int kb = 0; kb < 2; ++kb) {
                int row = wave * 16 + l15;
                qf[kb] = *(const b16x8*)(Qs + row * 64 + (((kb * 4 + quad) ^ (row & 7)) * 8));
            }
        }

        // S^T = K Q^T  (A=K-frag, B=Q-frag)
        f32x4 st[4];   // mt token-tiles: token = mt*16+quad*4+r, qrow = l15
        #pragma unroll
        for (int mt = 0; mt < 4; ++mt) st[mt] = (f32x4){0.f, 0.f, 0.f, 0.f};
        #pragma unroll
        for (int mt = 0; mt < 4; ++mt) {
            int trow = mt * 16 + l15;
            #pragma unroll
            for (int kb = 0; kb < 2; ++kb) {
                b16x8 kf = *(const b16x8*)(Ks + trow * 64 + (((kb * 4 + quad) ^ (trow & 7)) * 8));
                st[mt] = MFMA16(kf, qf[kb], st[mt]);
            }
        }

        // causal mask + P = exp2(S*SC2) (no max subtraction)
        const bool diag = (kj == qi);
        float rs = 0.0f;
        b16x4 pf[4];   // P^T fragments: directly in 16x16x16 B-operand layout
        #pragma unroll
        for (int mt = 0; mt < 4; ++mt)
            #pragma unroll
            for (int r = 0; r < 4; ++r) {
                float s = st[mt][r];
                if (diag && (mt * 16 + quad * 4 + r) > qrow_rel) s = NEGINF_;
                float e = EXP2F(s * SC2_);
                rs += e;
                pf[mt][r] = f2bf_trunc(e);
            }
        rs += __shfl_xor(rs, 16);
        rs += __shfl_xor(rs, 32);
        lrow += rs;
        // O^T += V^T P^T  (16x16x16; A=V^T-frag from swizzled Vt, B=P^T in regs)
        #pragma unroll
        for (int dt = 0; dt < 4; ++dt) {
            const short* vrow = Vt + (dt * 16 + l15) * 64;
            #pragma unroll
            for (int kt = 0; kt < 4; ++kt) {
                b16x4 vf = *(const b16x4*)(vrow + (((kt * 4 + quad) ^ l15) << 2));
                ot[dt] = MFMA16K16(vf, pf[kt], ot[dt]);
            }
        }
    }

    // epilogue: normalize, repack via same-wave LDS strip (Qs alias), store
    __syncthreads();   // all waves done reading Ks/Vt AND Qs fragments
    float inv = 1.0f / lrow;
    #pragma unroll
    for (int dt = 0; dt < 4; ++dt) {
        b16x4 o4;
        o4[0] = f2bf(ot[dt][0] * inv);
        o4[1] = f2bf(ot[dt][1] * inv);
        o4[2] = f2bf(ot[dt][2] * inv);
        o4[3] = f2bf(ot[dt][3] * inv);
        *(b16x4*)(Qs + (size_t)qrow_rel * 72 + dt * 16 + quad * 4) = o4;
    }
    // rows tid>>2 land inside this wave's own strip -> DS in-order, no barrier
    {
        int row = tid >> 2, ch = tid & 3;
        b16x8 lo = *(const b16x8*)(Qs + (size_t)row * 72 + ch * 16);
        b16x8 hi = *(const b16x8*)(Qs + (size_t)row * 72 + ch * 16 + 8);
        short* dst = Op + row * 64 + ch * 16;
        *(b16x8*)dst = lo;
        *(b16x8*)(dst + 8) = hi;
    }
    if (quad == 0) mlp[qrow_rel] = lrow;
}

// ---------------------------------------------------------------------------
// Combine the two attn split-K partials: O = (l1*O1 + l2*O2)/(l1+l2).
// ---------------------------------------------------------------------------
__global__ __launch_bounds__(256) void attn_combine_kernel(
        const short* __restrict__ Opart, const float* __restrict__ Ml,
        short* __restrict__ Ob)
{
    int pair = blockIdx.x;              // bh*32 + qi
    int bh = pair >> 5, qi = pair & 31;
    int b = bh >> 3, h = bh & 7;
    int tid = threadIdx.x;
    const short* O1 = Opart + (size_t)pair * 4096;
    const short* O2 = Opart + (size_t)(1024 + pair) * 4096;
    const float* ml1 = Ml + (size_t)pair * 64;
    const float* ml2 = Ml + (size_t)(1024 + pair) * 64;
    int ch = tid & 7;                   // 8 shorts per chunk
    #pragma unroll
    for (int it = 0; it < 2; ++it) {
        int row = it * 32 + (tid >> 3);
        float l1 = ml1[row], l2 = ml2[row];
        float inv = 1.0f / (l1 + l2);
        float w1 = l1 * inv, w2 = l2 * inv;
        b16x8 a = *(const b16x8*)(O1 + row * 64 + ch * 8);
        b16x8 c = *(const b16x8*)(O2 + row * 64 + ch * 8);
        b16x8 o;
        #pragma unroll
        for (int e = 0; e < 8; ++e)
            o[e] = f2bf(w1 * bf2f(a[e]) + w2 * bf2f(c[e]));
        short* dst = Ob + ((size_t)(b * T_ + qi * 64 + row)) * 512 + h * 64 + ch * 8;
        *(b16x8*)dst = o;
    }
}

// ---------------------------------------------------------------------------
extern "C" void kernel_launch(void* const* d_in, const int* in_sizes, int n_in,
                              void* d_out, int out_size, void* d_ws, size_t ws_size,
                              hipStream_t stream) {
    (void)in_sizes; (void)n_in; (void)out_size; (void)ws_size;
    const float* x     = (const float*)d_in[0];
    const float* ln_g  = (const float*)d_in[1];
    const float* ln_b  = (const float*)d_in[2];
    const float* Wq    = (const float*)d_in[3];
    const float* Wk    = (const float*)d_in[4];
    const float* Wv    = (const float*)d_in[5];
    const float* Wproj = (const float*)d_in[6];
    const float* bproj = (const float*)d_in[7];
    const float* W1    = (const float*)d_in[8];
    const float* b1    = (const float*)d_in[9];
    const float* W2    = (const float*)d_in[10];
    const float* b2    = (const float*)d_in[11];
    float* out = (float*)d_out;

    char* W = (char*)d_ws;
    short* hbuf  = (short*)(W + 0);                    // 8 MB  (LN out, bf16)
    short* qkvb  = (short*)(W + ((size_t)8  << 20));   // 24 MB [BT][1536]
    short* attno = (short*)(W + ((size_t)32 << 20));   // 8 MB  [BT][512]
    short* x1b   = (short*)(W + ((size_t)40 << 20));   // 8 MB  [BT][512] bf16
    short* ff1   = (short*)(W + ((size_t)56 << 20));   // 32 MB [BT][2048]
    short* wqkv  = (short*)(W + ((size_t)88 << 20));   // 1.5 MB [1536][512]
    short* wpt   = (short*)(W + ((size_t)90 << 20));   // 0.5 MB [512][512]
    short* w1t   = (short*)(W + ((size_t)91 << 20));   // 2 MB  [2048][512]
    short* w2t   = (short*)(W + ((size_t)93 << 20));   // 2 MB  [512][2048]
    short* Opart = (short*)(W + ((size_t)96 << 20));   // 16 MB [2][1024][64][64] bf16
    float* Ml    = (float*)(W + ((size_t)112 << 20));  // 0.5 MB [2][1024][64] fp32

    // 0. weight transposes + LN1 fused in one launch
    prologue_kernel<<<dim3(3072 + BT_ / 4), dim3(32, 8), 0, stream>>>(
        Wq, Wk, Wv, Wproj, W1, W2, wqkv, wpt, w1t, w2t,
        x, ln_g, ln_b, hbuf);
    // 1. qkv = h @ Wqkv  [8192,1536] bf16  (256x256 tiles -> 192 blocks)
    mm256_kernel<<<dim3(32, 6), dim3(512), 0, stream>>>(hbuf, wqkv, qkvb,
        nullptr, 0, 1536, D_);
    // 2. attention split-K x2 -> partials, then combine -> attno bf16
    attn_kernel<<<dim3(32, 32, 2), dim3(256), 0, stream>>>(qkvb, Opart, Ml);
    attn_combine_kernel<<<dim3(1024), dim3(256), 0, stream>>>(Opart, Ml, attno);
    // 3. x1b = bf16(x + attno @ Wproj + bproj)   (BK=64 -> 16 iters)
    mm6464_kernel<<<dim3(128, 8), dim3(256), 0, stream>>>(attno, wpt, x1b,
        bproj, x, BT_, D_, D_, 0, 1, 0);
    // 4. h2 = LN(x1b) -> bf16 (reuse hbuf)
    ln_bf16_kernel<<<dim3(BT_ / 4), dim3(256), 0, stream>>>(x1b, ln_g, ln_b, hbuf);
    // 5. ff1 = relu(h2 @ W1 + b1)  bf16  (256x256 tiles -> 256 blocks = 1/CU)
    mm256_kernel<<<dim3(32, 8), dim3(512), 0, stream>>>(hbuf, w1t, ff1,
        b1, 1, FF_, D_);
    // 6. out = x1b + ff1 @ W2 + b2  (fp32 out, bf16 resid, BK=64 -> 32 iters)
    mm6464_kernel<<<dim3(128, 8), dim3(256), 0, stream>>>(ff1, w2t, out,
        b2, x1b, BT_, D_, FF_, 0, 0, 1);
}